// Round 4
// baseline (252.579 us; speedup 1.0000x reference)
//
#include <hip/hip_runtime.h>
#include <hip/hip_bf16.h>
#include <stdint.h>

#define B_ 4
#define N_ 4096
#define D_ 64
#define K_ 16

// ---------------- workspace layout (float-element offsets) ----------------
static const size_t OFS_WQA1  = 0;                      // Wq@A1      [64x64]
static const size_t OFS_WKA1  = 4096;                   // Wk@A1      [64x64]
static const size_t OFS_WCOMB = 8192;                   // [c][dd] dd<64: P2@A1, dd>=64: P2   [64x128]
static const size_t OFS_C1    = 16384;                  // p2b@A1 + a1b  [64]
static const size_t OFS_QA1   = 16448;                  // x@WqA1     [B*N*64]
static const size_t OFS_KA1   = OFS_QA1 + (size_t)B_*N_*64;
static const size_t OFS_V     = OFS_KA1 + (size_t)B_*N_*64;
static const size_t OFS_IDX   = OFS_V   + (size_t)B_*N_*64;           // int [B*N*16]
static const size_t OFS_POS4  = OFS_IDX + (size_t)B_*N_*16;           // float4 [B*N] (byte%16==0)

typedef __attribute__((ext_vector_type(8))) short short8;
typedef __attribute__((ext_vector_type(4))) float floatx4;

__device__ __forceinline__ unsigned short f2bf(float f) {
    __hip_bfloat16 h = __float2bfloat16(f);
    return *reinterpret_cast<unsigned short*>(&h);
}

__device__ __forceinline__ unsigned long long bsortu64(unsigned long long v, int l) {
#pragma unroll
    for (int k = 2; k <= 64; k <<= 1) {
#pragma unroll
        for (int j = k >> 1; j > 0; j >>= 1) {
            unsigned long long o = __shfl_xor(v, j, 64);
            unsigned long long mn = v < o ? v : o;
            unsigned long long mx = v < o ? o : v;
            v = ((((l & j) == 0) == ((l & k) == 0))) ? mn : mx;
        }
    }
    return v;
}

// ---------------- kernel 1: tiny weight precompute ----------------
__global__ void k_precompute(const float* __restrict__ Wq, const float* __restrict__ Wk,
                             const float* __restrict__ P2, const float* __restrict__ A1,
                             const float* __restrict__ p2b, const float* __restrict__ a1b,
                             float* __restrict__ ws) {
    int i = blockIdx.x * 256 + threadIdx.x;
    if (i < 4096) {
        int c = i >> 6, d = i & 63;
        float s = 0.f;
        for (int e = 0; e < 64; ++e) s = fmaf(Wq[c*64+e], A1[e*64+d], s);
        ws[OFS_WQA1 + i] = s;
    } else if (i < 8192) {
        int j = i - 4096; int c = j >> 6, d = j & 63;
        float s = 0.f;
        for (int e = 0; e < 64; ++e) s = fmaf(Wk[c*64+e], A1[e*64+d], s);
        ws[OFS_WKA1 + j] = s;
    } else if (i < 16384) {
        int j = i - 8192; int c = j >> 7, dd = j & 127;
        float s;
        if (dd < 64) { s = 0.f; for (int e = 0; e < 64; ++e) s = fmaf(P2[c*64+e], A1[e*64+dd], s); }
        else s = P2[c*64 + (dd - 64)];
        ws[OFS_WCOMB + j] = s;
    } else if (i < 16448) {
        int d = i - 16384;
        float s = a1b[d];
        for (int e = 0; e < 64; ++e) s = fmaf(p2b[e], A1[e*64+d], s);
        ws[OFS_C1 + d] = s;
    }
}

// ---------------- kernel 1b: pos -> float4(x,y,z,|p|^2) ----------------
__global__ __launch_bounds__(256) void k_pos4(const float* __restrict__ pos,
                                              float* __restrict__ ws) {
    int i = blockIdx.x * 256 + threadIdx.x;    // 64 blocks -> 16384 points
    float px = pos[(size_t)i*3+0], py = pos[(size_t)i*3+1], pz = pos[(size_t)i*3+2];
    float sq = fmaf(pz, pz, fmaf(py, py, px*px));
    ((float4*)(ws + OFS_POS4))[i] = make_float4(px, py, pz, sq);
}

// ---------------- kernel 2: projections qA1,kA1,v (wave per row) ----------------
__global__ __launch_bounds__(256) void k_proj(const float* __restrict__ x,
                                              const float* __restrict__ Wv,
                                              float* __restrict__ ws) {
    int g = blockIdx.x * 4 + (threadIdx.x >> 6);     // global row 0..16383
    int d = threadIdx.x & 63;
    const float* WqA1 = ws + OFS_WQA1;
    const float* WkA1 = ws + OFS_WKA1;
    const float* xr = x + (size_t)g * 64;
    float aq = 0.f, ak = 0.f, av = 0.f;
#pragma unroll 8
    for (int c = 0; c < 64; ++c) {
        float xv = xr[c];
        aq = fmaf(xv, WqA1[c*64+d], aq);
        ak = fmaf(xv, WkA1[c*64+d], ak);
        av = fmaf(xv, Wv[c*64+d],   av);
    }
    ws[OFS_QA1 + (size_t)g*64 + d] = aq;
    ws[OFS_KA1 + (size_t)g*64 + d] = ak;
    ws[OFS_V   + (size_t)g*64 + d] = av;
}

// ---------------- kernel 3: exact threshold-filter kNN (wave per query) ----------
// Pass1: distances kept in 64 VGPRs; per-lane min -> full bitonic -> tau = 16th
//        smallest lane-min (combinatorial guarantee: >=16 cands <= tau).
// Pass2: register compare + ballot-compact (~18 survivors) into LDS. No recompute.
// Pass3: wave bitonic sort of (dist,idx) keys -> exact top-16 w/ tie->low idx.
__global__ __launch_bounds__(256, 4) void k_knn(float* __restrict__ ws) {
    __shared__ float4 tile[2048];                 // 32 KB (half of one batch)
    __shared__ unsigned long long sbuf[4*128];    // 4 KB survivor buffers
    const float4* pos4 = (const float4*)(ws + OFS_POS4);
    int* idx = (int*)(ws + OFS_IDX);
    const int t = threadIdx.x;
    const int l = t & 63, wv = t >> 6;
    const int b = (int)(blockIdx.x >> 10);
    const int q = ((int)blockIdx.x & 1023) * 4 + wv;
    const size_t grow = (size_t)b * N_ + q;
    const float4* pb = pos4 + (size_t)b * N_;

    float4 qp = pos4[grow];
    float dst[64];
    float mn = 1e30f;

    // ---- stage half0 + pass1 (distances -> registers) ----
#pragma unroll
    for (int i = 0; i < 8; ++i) tile[t + 256*i] = pb[t + 256*i];
    __syncthreads();
#pragma unroll
    for (int i = 0; i < 32; ++i) {
        float4 cd = tile[i*64 + l];
        float dot = fmaf(qp.z, cd.z, fmaf(qp.y, cd.y, qp.x*cd.x));
        float d = fmaxf(fmaf(-2.f, dot, qp.w + cd.w), 0.f);
        dst[i] = d;
        mn = fminf(mn, d);
    }
    __syncthreads();
    // ---- stage half1 + pass1 ----
#pragma unroll
    for (int i = 0; i < 8; ++i) tile[t + 256*i] = pb[2048 + t + 256*i];
    __syncthreads();
#pragma unroll
    for (int i = 0; i < 32; ++i) {
        float4 cd = tile[i*64 + l];
        float dot = fmaf(qp.z, cd.z, fmaf(qp.y, cd.y, qp.x*cd.x));
        float d = fmaxf(fmaf(-2.f, dot, qp.w + cd.w), 0.f);
        dst[32 + i] = d;
        mn = fminf(mn, d);
    }

    // ---- tau = 16th smallest of the 64 lane-minima (wave bitonic, float) ----
    float v = mn;
#pragma unroll
    for (int k = 2; k <= 64; k <<= 1) {
#pragma unroll
        for (int j = k >> 1; j > 0; j >>= 1) {
            float o = __shfl_xor(v, j, 64);
            float mnv = fminf(v, o), mxv = fmaxf(v, o);
            v = ((((l & j) == 0) == ((l & k) == 0))) ? mnv : mxv;
        }
    }
    float tau = __shfl(v, 15, 64);

    // ---- pass2: ballot-compact survivors from registers ----
    unsigned long long* sb = sbuf + wv*128;
    const unsigned long long lmask = (1ull << l) - 1ull;
    int cnt = 0;
#pragma unroll
    for (int i = 0; i < 64; ++i) {
        bool pred = (dst[i] <= tau);
        unsigned long long m = __ballot(pred);
        if (pred) {
            int pos2 = cnt + __popcll(m & lmask);
            if (pos2 < 128)
                sb[pos2] = ((unsigned long long)__float_as_uint(dst[i]) << 32)
                           | (unsigned)(i*64 + l);
        }
        cnt += (int)__popcll(m);
    }
    if (cnt > 128) cnt = 128;

    // ---- pass3: sort survivors, write top-16 ----
    unsigned long long pk = (l < cnt) ? sb[l] : ~0ull;
    pk = bsortu64(pk, l);
    if (cnt > 64) {   // wave-uniform, astronomically rare with tight tau
        unsigned long long w2 = (64 + l < cnt) ? sb[64 + l] : ~0ull;
        w2 = bsortu64(w2, l);
        unsigned long long bb = __shfl(w2, (l - 16) & 63, 64);
        unsigned long long nv = (l < 16) ? pk : ((l < 32) ? bb : ~0ull);
        pk = bsortu64(nv, l);
    }
    if (l < 16) idx[grow*16 + l] = (int)(pk & 0xffffffffu);
}

// ---------------- kernel 5: fused per-neighbor MLPs + softmax + agg + out ---------
// block = 256 threads (4 waves) handles 8 points = 128 (n,k) rows.
__global__ __launch_bounds__(256) void k_attn(
    const float* __restrict__ x, const float* __restrict__ pos,
    const float* __restrict__ P1, const float* __restrict__ p1b,
    const float* __restrict__ p2b, const float* __restrict__ a2b,
    const float* __restrict__ A2, const float* __restrict__ Wf,
    const float* __restrict__ bff, const float* __restrict__ ws,
    float* __restrict__ out) {

    __shared__ unsigned short wcombT[128*72];  // Bt: [dd][c]
    __shared__ unsigned short a2T[64*72];      // Bt: [d][e]
    __shared__ unsigned short abuf[128*72];    // h1 then h2, row-major [r][c], stride 72
    __shared__ float relb[128*4];
    __shared__ int   mrow[128];
    __shared__ float aggb[8*64];

    const int t  = threadIdx.x;
    const int g0 = blockIdx.x * 8;
    const int b  = g0 >> 12;
    const float* qA1 = ws + OFS_QA1;
    const float* kA1 = ws + OFS_KA1;
    const float* vws = ws + OFS_V;
    const float* c1  = ws + OFS_C1;
    const int* idx = (const int*)(ws + OFS_IDX);

    for (int i = t; i < 8192; i += 256) {
        int c = i >> 7, dd = i & 127;
        wcombT[dd*72 + c] = f2bf(ws[OFS_WCOMB + i]);
    }
    for (int i = t; i < 4096; i += 256) {
        int e = i >> 6, d = i & 63;
        a2T[d*72 + e] = f2bf(A2[i]);
    }
    if (t < 128) {
        int p = t >> 4, k = t & 15;
        int ng = g0 + p;
        int m  = idx[(size_t)ng*16 + k];
        int mg = b * N_ + m;
        mrow[t] = mg;
        relb[t*4+0] = pos[(size_t)ng*3+0] - pos[(size_t)mg*3+0];
        relb[t*4+1] = pos[(size_t)ng*3+1] - pos[(size_t)mg*3+1];
        relb[t*4+2] = pos[(size_t)ng*3+2] - pos[(size_t)mg*3+2];
    }
    __syncthreads();

    {
        int d = t & 63, r0 = t >> 6;
        float w0 = P1[d], w1 = P1[64+d], w2 = P1[128+d], bb = p1b[d];
#pragma unroll
        for (int jj = 0; jj < 32; ++jj) {
            int r = r0 + jj*4;
            float h = fmaf(relb[r*4+2], w2, fmaf(relb[r*4+1], w1, fmaf(relb[r*4+0], w0, bb)));
            abuf[r*72 + d] = f2bf(fmaxf(h, 0.f));
        }
    }
    __syncthreads();

    const int w = t >> 6, l = t & 63, lr = l & 15, q = l >> 4;

    floatx4 acc1[2][8];
#pragma unroll
    for (int i = 0; i < 2; ++i)
#pragma unroll
        for (int j = 0; j < 8; ++j) acc1[i][j] = (floatx4){0.f, 0.f, 0.f, 0.f};
#pragma unroll
    for (int kb = 0; kb < 2; ++kb) {
        short8 a0 = *(const short8*)&abuf[(32*w      + lr)*72 + 32*kb + 8*q];
        short8 a1 = *(const short8*)&abuf[(32*w + 16 + lr)*72 + 32*kb + 8*q];
#pragma unroll
        for (int j = 0; j < 8; ++j) {
            short8 bfr = *(const short8*)&wcombT[(16*j + lr)*72 + 32*kb + 8*q];
            acc1[0][j] = __builtin_amdgcn_mfma_f32_16x16x32_bf16(a0, bfr, acc1[0][j], 0, 0, 0);
            acc1[1][j] = __builtin_amdgcn_mfma_f32_16x16x32_bf16(a1, bfr, acc1[1][j], 0, 0, 0);
        }
    }
    __syncthreads();

#pragma unroll
    for (int i = 0; i < 2; ++i) {
        int ng = g0 + 2*w + i;
#pragma unroll
        for (int j = 0; j < 4; ++j) {
            int col = 16*j + lr;
            float qv = qA1[(size_t)ng*64 + col] + c1[col];
#pragma unroll
            for (int r = 0; r < 4; ++r) {
                int row = 32*w + 16*i + 4*q + r;
                int mg  = mrow[row];
                float t1 = acc1[i][j][r] + qv - kA1[(size_t)mg*64 + col];
                abuf[row*72 + col] = f2bf(fmaxf(t1, 0.f));
            }
        }
    }
    __syncthreads();

    floatx4 acc2[2][4];
#pragma unroll
    for (int i = 0; i < 2; ++i)
#pragma unroll
        for (int j = 0; j < 4; ++j) acc2[i][j] = (floatx4){0.f, 0.f, 0.f, 0.f};
#pragma unroll
    for (int kb = 0; kb < 2; ++kb) {
        short8 a0 = *(const short8*)&abuf[(32*w      + lr)*72 + 32*kb + 8*q];
        short8 a1 = *(const short8*)&abuf[(32*w + 16 + lr)*72 + 32*kb + 8*q];
#pragma unroll
        for (int j = 0; j < 4; ++j) {
            short8 bfr = *(const short8*)&a2T[(16*j + lr)*72 + 32*kb + 8*q];
            acc2[0][j] = __builtin_amdgcn_mfma_f32_16x16x32_bf16(a0, bfr, acc2[0][j], 0, 0, 0);
            acc2[1][j] = __builtin_amdgcn_mfma_f32_16x16x32_bf16(a1, bfr, acc2[1][j], 0, 0, 0);
        }
    }

#pragma unroll
    for (int i = 0; i < 2; ++i) {
#pragma unroll
        for (int j = 0; j < 4; ++j) {
            int col = 16*j + lr;
            float a2bv = a2b[col], p2bv = p2b[col];
            float L[4];
#pragma unroll
            for (int r = 0; r < 4; ++r) L[r] = acc2[i][j][r] + a2bv;
            float mx = fmaxf(fmaxf(L[0], L[1]), fmaxf(L[2], L[3]));
            mx = fmaxf(mx, __shfl_xor(mx, 16, 64));
            mx = fmaxf(mx, __shfl_xor(mx, 32, 64));
            float ssum = 0.f, part = 0.f;
#pragma unroll
            for (int r = 0; r < 4; ++r) {
                float e = __expf((L[r] - mx) * 0.125f);
                ssum += e;
                int row = 32*w + 16*i + 4*q + r;
                int mg  = mrow[row];
                float wv = vws[(size_t)mg*64 + col] + (acc1[i][4+j][r] + p2bv);
                part = fmaf(e, wv, part);
            }
            ssum += __shfl_xor(ssum, 16, 64);
            ssum += __shfl_xor(ssum, 32, 64);
            part += __shfl_xor(part, 16, 64);
            part += __shfl_xor(part, 32, 64);
            float agg = part / ssum;
            if (q == 0) aggb[(2*w + i)*64 + col] = agg;
        }
    }
    __syncthreads();

    {
        int d = t & 63;
        int p0 = t >> 6;
#pragma unroll
        for (int pp = p0; pp < 8; pp += 4) {
            float s = bff[d];
#pragma unroll 8
            for (int c = 0; c < 64; ++c) s = fmaf(aggb[pp*64 + c], Wf[c*64 + d], s);
            int g = g0 + pp;
            out[(size_t)g*64 + d] = s + x[(size_t)g*64 + d];
        }
    }
}

// ---------------- launch ----------------
extern "C" void kernel_launch(void* const* d_in, const int* in_sizes, int n_in,
                              void* d_out, int out_size, void* d_ws, size_t ws_size,
                              hipStream_t stream) {
    const float* x   = (const float*)d_in[0];
    const float* pos = (const float*)d_in[1];
    const float* Wq  = (const float*)d_in[2];
    const float* Wk  = (const float*)d_in[3];
    const float* Wv  = (const float*)d_in[4];
    const float* P1  = (const float*)d_in[5];
    const float* p1b = (const float*)d_in[6];
    const float* P2  = (const float*)d_in[7];
    const float* p2b = (const float*)d_in[8];
    const float* A1  = (const float*)d_in[9];
    const float* a1b = (const float*)d_in[10];
    const float* A2  = (const float*)d_in[11];
    const float* a2b = (const float*)d_in[12];
    const float* Wf  = (const float*)d_in[13];
    const float* bf  = (const float*)d_in[14];
    float* out = (float*)d_out;
    float* ws  = (float*)d_ws;

    hipLaunchKernelGGL(k_precompute, dim3(65),   dim3(256), 0, stream, Wq, Wk, P2, A1, p2b, a1b, ws);
    hipLaunchKernelGGL(k_pos4,       dim3(64),   dim3(256), 0, stream, pos, ws);
    hipLaunchKernelGGL(k_proj,       dim3(4096), dim3(256), 0, stream, x, Wv, ws);
    hipLaunchKernelGGL(k_knn,        dim3(4096), dim3(256), 0, stream, ws);
    hipLaunchKernelGGL(k_attn,       dim3(2048), dim3(256), 0, stream,
                       x, pos, P1, p1b, p2b, a2b, A2, Wf, bf, ws, out);
}

// Round 5
// 222.267 us; speedup vs baseline: 1.1364x; 1.1364x over previous
//
#include <hip/hip_runtime.h>
#include <hip/hip_bf16.h>
#include <stdint.h>

#define B_ 4
#define N_ 4096
#define D_ 64
#define K_ 16

// ---------------- workspace layout (float-element offsets) ----------------
static const size_t OFS_WQA1  = 0;                      // Wq@A1      [64x64]
static const size_t OFS_WKA1  = 4096;                   // Wk@A1      [64x64]
static const size_t OFS_WCOMB = 8192;                   // [c][dd] dd<64: P2@A1, dd>=64: P2   [64x128]
static const size_t OFS_C1    = 16384;                  // p2b@A1 + a1b  [64]
static const size_t OFS_QA1   = 16448;                  // x@WqA1     [B*N*64]
static const size_t OFS_KA1   = OFS_QA1 + (size_t)B_*N_*64;
static const size_t OFS_V     = OFS_KA1 + (size_t)B_*N_*64;
static const size_t OFS_IDX   = OFS_V   + (size_t)B_*N_*64;           // int [B*N*16]
static const size_t OFS_POS4  = OFS_IDX + (size_t)B_*N_*16;           // float4 [B*N] (byte%16==0)

typedef __attribute__((ext_vector_type(8))) short short8;
typedef __attribute__((ext_vector_type(4))) float floatx4;

__device__ __forceinline__ unsigned short f2bf(float f) {
    __hip_bfloat16 h = __float2bfloat16(f);
    return *reinterpret_cast<unsigned short*>(&h);
}

__device__ __forceinline__ unsigned long long bsortu64(unsigned long long v, int l) {
#pragma unroll
    for (int k = 2; k <= 64; k <<= 1) {
#pragma unroll
        for (int j = k >> 1; j > 0; j >>= 1) {
            unsigned long long o = __shfl_xor(v, j, 64);
            unsigned long long mn = v < o ? v : o;
            unsigned long long mx = v < o ? o : v;
            v = ((((l & j) == 0) == ((l & k) == 0))) ? mn : mx;
        }
    }
    return v;
}

// ---------------- kernel 1: tiny weight precompute ----------------
__global__ void k_precompute(const float* __restrict__ Wq, const float* __restrict__ Wk,
                             const float* __restrict__ P2, const float* __restrict__ A1,
                             const float* __restrict__ p2b, const float* __restrict__ a1b,
                             float* __restrict__ ws) {
    int i = blockIdx.x * 256 + threadIdx.x;
    if (i < 4096) {
        int c = i >> 6, d = i & 63;
        float s = 0.f;
        for (int e = 0; e < 64; ++e) s = fmaf(Wq[c*64+e], A1[e*64+d], s);
        ws[OFS_WQA1 + i] = s;
    } else if (i < 8192) {
        int j = i - 4096; int c = j >> 6, d = j & 63;
        float s = 0.f;
        for (int e = 0; e < 64; ++e) s = fmaf(Wk[c*64+e], A1[e*64+d], s);
        ws[OFS_WKA1 + j] = s;
    } else if (i < 16384) {
        int j = i - 8192; int c = j >> 7, dd = j & 127;
        float s;
        if (dd < 64) { s = 0.f; for (int e = 0; e < 64; ++e) s = fmaf(P2[c*64+e], A1[e*64+dd], s); }
        else s = P2[c*64 + (dd - 64)];
        ws[OFS_WCOMB + j] = s;
    } else if (i < 16448) {
        int d = i - 16384;
        float s = a1b[d];
        for (int e = 0; e < 64; ++e) s = fmaf(p2b[e], A1[e*64+d], s);
        ws[OFS_C1 + d] = s;
    }
}

// ---------------- kernel 1b: pos -> float4(x,y,z,|p|^2) ----------------
__global__ __launch_bounds__(256) void k_pos4(const float* __restrict__ pos,
                                              float* __restrict__ ws) {
    int i = blockIdx.x * 256 + threadIdx.x;    // 64 blocks -> 16384 points
    float px = pos[(size_t)i*3+0], py = pos[(size_t)i*3+1], pz = pos[(size_t)i*3+2];
    float sq = fmaf(pz, pz, fmaf(py, py, px*px));
    ((float4*)(ws + OFS_POS4))[i] = make_float4(px, py, pz, sq);
}

// ---------------- kernel 2: projections qA1,kA1,v (wave per row) ----------------
__global__ __launch_bounds__(256) void k_proj(const float* __restrict__ x,
                                              const float* __restrict__ Wv,
                                              float* __restrict__ ws) {
    int g = blockIdx.x * 4 + (threadIdx.x >> 6);     // global row 0..16383
    int d = threadIdx.x & 63;
    const float* WqA1 = ws + OFS_WQA1;
    const float* WkA1 = ws + OFS_WKA1;
    const float* xr = x + (size_t)g * 64;
    float aq = 0.f, ak = 0.f, av = 0.f;
#pragma unroll 8
    for (int c = 0; c < 64; ++c) {
        float xv = xr[c];
        aq = fmaf(xv, WqA1[c*64+d], aq);
        ak = fmaf(xv, WkA1[c*64+d], ak);
        av = fmaf(xv, Wv[c*64+d],   av);
    }
    ws[OFS_QA1 + (size_t)g*64 + d] = aq;
    ws[OFS_KA1 + (size_t)g*64 + d] = ak;
    ws[OFS_V   + (size_t)g*64 + d] = av;
}

// ---------------- kernel 3: exact threshold-filter kNN (wave per query) ----------
// Half0 distances kept in 32 VGPRs (no spill: ~84 VGPR total < 128 cap).
// Half1 stays LDS-resident through pass2 and is recomputed from the tile
// (bit-identical fma chain). tau = 16th smallest lane-min (>=16 cands <= tau).
__global__ __launch_bounds__(256, 4) void k_knn(float* __restrict__ ws) {
    __shared__ float4 tile[2048];                 // 32 KB (half of one batch)
    __shared__ unsigned long long sbuf[4*128];    // 4 KB survivor buffers
    const float4* pos4 = (const float4*)(ws + OFS_POS4);
    int* idx = (int*)(ws + OFS_IDX);
    const int t = threadIdx.x;
    const int l = t & 63, wv = t >> 6;
    const int b = (int)(blockIdx.x >> 10);
    const int q = ((int)blockIdx.x & 1023) * 4 + wv;
    const size_t grow = (size_t)b * N_ + q;
    const float4* pb = pos4 + (size_t)b * N_;

    float4 qp = pos4[grow];
    float dst0[32];
    float mn = 1e30f;

    // ---- stage half0 + pass1 (distances -> 32 registers) ----
#pragma unroll
    for (int i = 0; i < 8; ++i) tile[t + 256*i] = pb[t + 256*i];
    __syncthreads();
#pragma unroll
    for (int i = 0; i < 32; ++i) {
        float4 cd = tile[i*64 + l];
        float dot = fmaf(qp.z, cd.z, fmaf(qp.y, cd.y, qp.x*cd.x));
        float d = fmaxf(fmaf(-2.f, dot, qp.w + cd.w), 0.f);
        dst0[i] = d;
        mn = fminf(mn, d);
    }
    __syncthreads();
    // ---- stage half1 + pass1 (min only; tile stays resident for pass2) ----
#pragma unroll
    for (int i = 0; i < 8; ++i) tile[t + 256*i] = pb[2048 + t + 256*i];
    __syncthreads();
#pragma unroll 8
    for (int i = 0; i < 32; ++i) {
        float4 cd = tile[i*64 + l];
        float dot = fmaf(qp.z, cd.z, fmaf(qp.y, cd.y, qp.x*cd.x));
        float d = fmaxf(fmaf(-2.f, dot, qp.w + cd.w), 0.f);
        mn = fminf(mn, d);
    }

    // ---- tau = 16th smallest of the 64 lane-minima (wave bitonic, float) ----
    float v = mn;
#pragma unroll
    for (int k = 2; k <= 64; k <<= 1) {
#pragma unroll
        for (int j = k >> 1; j > 0; j >>= 1) {
            float o = __shfl_xor(v, j, 64);
            float mnv = fminf(v, o), mxv = fmaxf(v, o);
            v = ((((l & j) == 0) == ((l & k) == 0))) ? mnv : mxv;
        }
    }
    float tau = __shfl(v, 15, 64);

    // ---- pass2: ballot-compact survivors ----
    unsigned long long* sb = sbuf + wv*128;
    const unsigned long long lmask = (1ull << l) - 1ull;
    int cnt = 0;
    // half0 from registers
#pragma unroll
    for (int i = 0; i < 32; ++i) {
        bool pred = (dst0[i] <= tau);
        unsigned long long m = __ballot(pred);
        if (pred) {
            int pos2 = cnt + __popcll(m & lmask);
            if (pos2 < 128)
                sb[pos2] = ((unsigned long long)__float_as_uint(dst0[i]) << 32)
                           | (unsigned)(i*64 + l);
        }
        cnt += (int)__popcll(m);
    }
    // half1 recomputed from resident tile (bit-identical chain)
#pragma unroll 4
    for (int i = 0; i < 32; ++i) {
        float4 cd = tile[i*64 + l];
        float dot = fmaf(qp.z, cd.z, fmaf(qp.y, cd.y, qp.x*cd.x));
        float d = fmaxf(fmaf(-2.f, dot, qp.w + cd.w), 0.f);
        bool pred = (d <= tau);
        unsigned long long m = __ballot(pred);
        if (pred) {
            int pos2 = cnt + __popcll(m & lmask);
            if (pos2 < 128)
                sb[pos2] = ((unsigned long long)__float_as_uint(d) << 32)
                           | (unsigned)(2048 + i*64 + l);
        }
        cnt += (int)__popcll(m);
    }
    if (cnt > 128) cnt = 128;

    // ---- pass3: sort survivors, write top-16 ----
    unsigned long long pk = (l < cnt) ? sb[l] : ~0ull;
    pk = bsortu64(pk, l);
    if (cnt > 64) {   // wave-uniform, astronomically rare with tight tau
        unsigned long long w2 = (64 + l < cnt) ? sb[64 + l] : ~0ull;
        w2 = bsortu64(w2, l);
        unsigned long long bb = __shfl(w2, (l - 16) & 63, 64);
        unsigned long long nv = (l < 16) ? pk : ((l < 32) ? bb : ~0ull);
        pk = bsortu64(nv, l);
    }
    if (l < 16) idx[grow*16 + l] = (int)(pk & 0xffffffffu);
}

// ---------------- kernel 5: fused per-neighbor MLPs + softmax + agg + out ---------
// block = 256 threads (4 waves) handles 8 points = 128 (n,k) rows.
__global__ __launch_bounds__(256) void k_attn(
    const float* __restrict__ x, const float* __restrict__ pos,
    const float* __restrict__ P1, const float* __restrict__ p1b,
    const float* __restrict__ p2b, const float* __restrict__ a2b,
    const float* __restrict__ A2, const float* __restrict__ Wf,
    const float* __restrict__ bff, const float* __restrict__ ws,
    float* __restrict__ out) {

    __shared__ unsigned short wcombT[128*72];  // Bt: [dd][c]
    __shared__ unsigned short a2T[64*72];      // Bt: [d][e]
    __shared__ unsigned short abuf[128*72];    // h1 then h2, row-major [r][c], stride 72
    __shared__ float relb[128*4];
    __shared__ int   mrow[128];
    __shared__ float aggb[8*64];

    const int t  = threadIdx.x;
    const int g0 = blockIdx.x * 8;
    const int b  = g0 >> 12;
    const float* qA1 = ws + OFS_QA1;
    const float* kA1 = ws + OFS_KA1;
    const float* vws = ws + OFS_V;
    const float* c1  = ws + OFS_C1;
    const int* idx = (const int*)(ws + OFS_IDX);

    for (int i = t; i < 8192; i += 256) {
        int c = i >> 7, dd = i & 127;
        wcombT[dd*72 + c] = f2bf(ws[OFS_WCOMB + i]);
    }
    for (int i = t; i < 4096; i += 256) {
        int e = i >> 6, d = i & 63;
        a2T[d*72 + e] = f2bf(A2[i]);
    }
    if (t < 128) {
        int p = t >> 4, k = t & 15;
        int ng = g0 + p;
        int m  = idx[(size_t)ng*16 + k];
        int mg = b * N_ + m;
        mrow[t] = mg;
        relb[t*4+0] = pos[(size_t)ng*3+0] - pos[(size_t)mg*3+0];
        relb[t*4+1] = pos[(size_t)ng*3+1] - pos[(size_t)mg*3+1];
        relb[t*4+2] = pos[(size_t)ng*3+2] - pos[(size_t)mg*3+2];
    }
    __syncthreads();

    {
        int d = t & 63, r0 = t >> 6;
        float w0 = P1[d], w1 = P1[64+d], w2 = P1[128+d], bb = p1b[d];
#pragma unroll
        for (int jj = 0; jj < 32; ++jj) {
            int r = r0 + jj*4;
            float h = fmaf(relb[r*4+2], w2, fmaf(relb[r*4+1], w1, fmaf(relb[r*4+0], w0, bb)));
            abuf[r*72 + d] = f2bf(fmaxf(h, 0.f));
        }
    }
    __syncthreads();

    const int w = t >> 6, l = t & 63, lr = l & 15, q = l >> 4;

    floatx4 acc1[2][8];
#pragma unroll
    for (int i = 0; i < 2; ++i)
#pragma unroll
        for (int j = 0; j < 8; ++j) acc1[i][j] = (floatx4){0.f, 0.f, 0.f, 0.f};
#pragma unroll
    for (int kb = 0; kb < 2; ++kb) {
        short8 a0 = *(const short8*)&abuf[(32*w      + lr)*72 + 32*kb + 8*q];
        short8 a1 = *(const short8*)&abuf[(32*w + 16 + lr)*72 + 32*kb + 8*q];
#pragma unroll
        for (int j = 0; j < 8; ++j) {
            short8 bfr = *(const short8*)&wcombT[(16*j + lr)*72 + 32*kb + 8*q];
            acc1[0][j] = __builtin_amdgcn_mfma_f32_16x16x32_bf16(a0, bfr, acc1[0][j], 0, 0, 0);
            acc1[1][j] = __builtin_amdgcn_mfma_f32_16x16x32_bf16(a1, bfr, acc1[1][j], 0, 0, 0);
        }
    }
    __syncthreads();

#pragma unroll
    for (int i = 0; i < 2; ++i) {
        int ng = g0 + 2*w + i;
#pragma unroll
        for (int j = 0; j < 4; ++j) {
            int col = 16*j + lr;
            float qv = qA1[(size_t)ng*64 + col] + c1[col];
#pragma unroll
            for (int r = 0; r < 4; ++r) {
                int row = 32*w + 16*i + 4*q + r;
                int mg  = mrow[row];
                float t1 = acc1[i][j][r] + qv - kA1[(size_t)mg*64 + col];
                abuf[row*72 + col] = f2bf(fmaxf(t1, 0.f));
            }
        }
    }
    __syncthreads();

    floatx4 acc2[2][4];
#pragma unroll
    for (int i = 0; i < 2; ++i)
#pragma unroll
        for (int j = 0; j < 4; ++j) acc2[i][j] = (floatx4){0.f, 0.f, 0.f, 0.f};
#pragma unroll
    for (int kb = 0; kb < 2; ++kb) {
        short8 a0 = *(const short8*)&abuf[(32*w      + lr)*72 + 32*kb + 8*q];
        short8 a1 = *(const short8*)&abuf[(32*w + 16 + lr)*72 + 32*kb + 8*q];
#pragma unroll
        for (int j = 0; j < 4; ++j) {
            short8 bfr = *(const short8*)&a2T[(16*j + lr)*72 + 32*kb + 8*q];
            acc2[0][j] = __builtin_amdgcn_mfma_f32_16x16x32_bf16(a0, bfr, acc2[0][j], 0, 0, 0);
            acc2[1][j] = __builtin_amdgcn_mfma_f32_16x16x32_bf16(a1, bfr, acc2[1][j], 0, 0, 0);
        }
    }

#pragma unroll
    for (int i = 0; i < 2; ++i) {
#pragma unroll
        for (int j = 0; j < 4; ++j) {
            int col = 16*j + lr;
            float a2bv = a2b[col], p2bv = p2b[col];
            float L[4];
#pragma unroll
            for (int r = 0; r < 4; ++r) L[r] = acc2[i][j][r] + a2bv;
            float mx = fmaxf(fmaxf(L[0], L[1]), fmaxf(L[2], L[3]));
            mx = fmaxf(mx, __shfl_xor(mx, 16, 64));
            mx = fmaxf(mx, __shfl_xor(mx, 32, 64));
            float ssum = 0.f, part = 0.f;
#pragma unroll
            for (int r = 0; r < 4; ++r) {
                float e = __expf((L[r] - mx) * 0.125f);
                ssum += e;
                int row = 32*w + 16*i + 4*q + r;
                int mg  = mrow[row];
                float wv = vws[(size_t)mg*64 + col] + (acc1[i][4+j][r] + p2bv);
                part = fmaf(e, wv, part);
            }
            ssum += __shfl_xor(ssum, 16, 64);
            ssum += __shfl_xor(ssum, 32, 64);
            part += __shfl_xor(part, 16, 64);
            part += __shfl_xor(part, 32, 64);
            float agg = part / ssum;
            if (q == 0) aggb[(2*w + i)*64 + col] = agg;
        }
    }
    __syncthreads();

    {
        int d = t & 63;
        int p0 = t >> 6;
#pragma unroll
        for (int pp = p0; pp < 8; pp += 4) {
            float s = bff[d];
#pragma unroll 8
            for (int c = 0; c < 64; ++c) s = fmaf(aggb[pp*64 + c], Wf[c*64 + d], s);
            int g = g0 + pp;
            out[(size_t)g*64 + d] = s + x[(size_t)g*64 + d];
        }
    }
}

// ---------------- launch ----------------
extern "C" void kernel_launch(void* const* d_in, const int* in_sizes, int n_in,
                              void* d_out, int out_size, void* d_ws, size_t ws_size,
                              hipStream_t stream) {
    const float* x   = (const float*)d_in[0];
    const float* pos = (const float*)d_in[1];
    const float* Wq  = (const float*)d_in[2];
    const float* Wk  = (const float*)d_in[3];
    const float* Wv  = (const float*)d_in[4];
    const float* P1  = (const float*)d_in[5];
    const float* p1b = (const float*)d_in[6];
    const float* P2  = (const float*)d_in[7];
    const float* p2b = (const float*)d_in[8];
    const float* A1  = (const float*)d_in[9];
    const float* a1b = (const float*)d_in[10];
    const float* A2  = (const float*)d_in[11];
    const float* a2b = (const float*)d_in[12];
    const float* Wf  = (const float*)d_in[13];
    const float* bf  = (const float*)d_in[14];
    float* out = (float*)d_out;
    float* ws  = (float*)d_ws;

    hipLaunchKernelGGL(k_precompute, dim3(65),   dim3(256), 0, stream, Wq, Wk, P2, A1, p2b, a1b, ws);
    hipLaunchKernelGGL(k_pos4,       dim3(64),   dim3(256), 0, stream, pos, ws);
    hipLaunchKernelGGL(k_proj,       dim3(4096), dim3(256), 0, stream, x, Wv, ws);
    hipLaunchKernelGGL(k_knn,        dim3(4096), dim3(256), 0, stream, ws);
    hipLaunchKernelGGL(k_attn,       dim3(2048), dim3(256), 0, stream,
                       x, pos, P1, p1b, p2b, a2b, A2, Wf, bf, ws, out);
}

// Round 6
// 216.019 us; speedup vs baseline: 1.1692x; 1.0289x over previous
//
#include <hip/hip_runtime.h>
#include <hip/hip_bf16.h>
#include <stdint.h>

#define B_ 4
#define N_ 4096
#define D_ 64
#define K_ 16

// ---------------- workspace layout (float-element offsets) ----------------
static const size_t OFS_WQA1  = 0;                      // Wq@A1      [64x64]
static const size_t OFS_WKA1  = 4096;                   // Wk@A1      [64x64]
static const size_t OFS_WCOMB = 8192;                   // [c][dd] dd<64: P2@A1, dd>=64: P2   [64x128]
static const size_t OFS_C1    = 16384;                  // p2b@A1 + a1b  [64]
static const size_t OFS_QA1   = 16448;                  // x@WqA1     [B*N*64]
static const size_t OFS_KA1   = OFS_QA1 + (size_t)B_*N_*64;
static const size_t OFS_V     = OFS_KA1 + (size_t)B_*N_*64;
static const size_t OFS_IDX   = OFS_V   + (size_t)B_*N_*64;           // int [B*N*16]
static const size_t OFS_POS4  = OFS_IDX + (size_t)B_*N_*16;           // float4 [B*N] (byte%16==0)

typedef __attribute__((ext_vector_type(8))) short short8;
typedef __attribute__((ext_vector_type(4))) float floatx4;

__device__ __forceinline__ unsigned short f2bf(float f) {
    __hip_bfloat16 h = __float2bfloat16(f);
    return *reinterpret_cast<unsigned short*>(&h);
}

__device__ __forceinline__ unsigned long long bsortu64(unsigned long long v, int l) {
#pragma unroll
    for (int k = 2; k <= 64; k <<= 1) {
#pragma unroll
        for (int j = k >> 1; j > 0; j >>= 1) {
            unsigned long long o = __shfl_xor(v, j, 64);
            unsigned long long mn = v < o ? v : o;
            unsigned long long mx = v < o ? o : v;
            v = ((((l & j) == 0) == ((l & k) == 0))) ? mn : mx;
        }
    }
    return v;
}

// ---------------- kernel 1: tiny weight precompute ----------------
__global__ void k_precompute(const float* __restrict__ Wq, const float* __restrict__ Wk,
                             const float* __restrict__ P2, const float* __restrict__ A1,
                             const float* __restrict__ p2b, const float* __restrict__ a1b,
                             float* __restrict__ ws) {
    int i = blockIdx.x * 256 + threadIdx.x;
    if (i < 4096) {
        int c = i >> 6, d = i & 63;
        float s = 0.f;
        for (int e = 0; e < 64; ++e) s = fmaf(Wq[c*64+e], A1[e*64+d], s);
        ws[OFS_WQA1 + i] = s;
    } else if (i < 8192) {
        int j = i - 4096; int c = j >> 6, d = j & 63;
        float s = 0.f;
        for (int e = 0; e < 64; ++e) s = fmaf(Wk[c*64+e], A1[e*64+d], s);
        ws[OFS_WKA1 + j] = s;
    } else if (i < 16384) {
        int j = i - 8192; int c = j >> 7, dd = j & 127;
        float s;
        if (dd < 64) { s = 0.f; for (int e = 0; e < 64; ++e) s = fmaf(P2[c*64+e], A1[e*64+dd], s); }
        else s = P2[c*64 + (dd - 64)];
        ws[OFS_WCOMB + j] = s;
    } else if (i < 16448) {
        int d = i - 16384;
        float s = a1b[d];
        for (int e = 0; e < 64; ++e) s = fmaf(p2b[e], A1[e*64+d], s);
        ws[OFS_C1 + d] = s;
    }
}

// ---------------- kernel 1b: pos -> float4(x,y,z,|p|^2) ----------------
__global__ __launch_bounds__(256) void k_pos4(const float* __restrict__ pos,
                                              float* __restrict__ ws) {
    int i = blockIdx.x * 256 + threadIdx.x;    // 64 blocks -> 16384 points
    float px = pos[(size_t)i*3+0], py = pos[(size_t)i*3+1], pz = pos[(size_t)i*3+2];
    float sq = fmaf(pz, pz, fmaf(py, py, px*px));
    ((float4*)(ws + OFS_POS4))[i] = make_float4(px, py, pz, sq);
}

// ---------------- kernel 2: projections qA1,kA1,v (wave per row) ----------------
__global__ __launch_bounds__(256) void k_proj(const float* __restrict__ x,
                                              const float* __restrict__ Wv,
                                              float* __restrict__ ws) {
    int g = blockIdx.x * 4 + (threadIdx.x >> 6);     // global row 0..16383
    int d = threadIdx.x & 63;
    const float* WqA1 = ws + OFS_WQA1;
    const float* WkA1 = ws + OFS_WKA1;
    const float* xr = x + (size_t)g * 64;
    float aq = 0.f, ak = 0.f, av = 0.f;
#pragma unroll 8
    for (int c = 0; c < 64; ++c) {
        float xv = xr[c];
        aq = fmaf(xv, WqA1[c*64+d], aq);
        ak = fmaf(xv, WkA1[c*64+d], ak);
        av = fmaf(xv, Wv[c*64+d],   av);
    }
    ws[OFS_QA1 + (size_t)g*64 + d] = aq;
    ws[OFS_KA1 + (size_t)g*64 + d] = ak;
    ws[OFS_V   + (size_t)g*64 + d] = av;
}

// ---------------- kernel 3: exact threshold-filter kNN (wave per query) ----------
// Half0 distances kept in 32 VGPRs; half1 recomputed from the LDS-resident tile
// (bit-identical fma chain). tau = 16th smallest lane-min (>=16 cands <= tau).
// NOTE: no min-waves arg in __launch_bounds__ — with (256,4) the allocator
// targeted 8 waves/EU (VGPR_Count=64) and spilled the whole dst array to
// scratch (R4: 156 MB, R5: 72 MB scratch writes). LDS (36 KB -> 4 blk/CU)
// already pins occupancy; let the allocator use ~100 VGPRs freely.
__global__ __launch_bounds__(256) void k_knn(float* __restrict__ ws) {
    __shared__ float4 tile[2048];                 // 32 KB (half of one batch)
    __shared__ unsigned long long sbuf[4*128];    // 4 KB survivor buffers
    const float4* pos4 = (const float4*)(ws + OFS_POS4);
    int* idx = (int*)(ws + OFS_IDX);
    const int t = threadIdx.x;
    const int l = t & 63, wv = t >> 6;
    const int b = (int)(blockIdx.x >> 10);
    const int q = ((int)blockIdx.x & 1023) * 4 + wv;
    const size_t grow = (size_t)b * N_ + q;
    const float4* pb = pos4 + (size_t)b * N_;

    float4 qp = pos4[grow];
    float dst0[32];
    float mn = 1e30f;

    // ---- stage half0 + pass1 (distances -> 32 registers) ----
#pragma unroll
    for (int i = 0; i < 8; ++i) tile[t + 256*i] = pb[t + 256*i];
    __syncthreads();
#pragma unroll 8
    for (int i = 0; i < 32; ++i) {
        float4 cd = tile[i*64 + l];
        float dot = fmaf(qp.z, cd.z, fmaf(qp.y, cd.y, qp.x*cd.x));
        float d = fmaxf(fmaf(-2.f, dot, qp.w + cd.w), 0.f);
        dst0[i] = d;
        mn = fminf(mn, d);
    }
    __syncthreads();
    // ---- stage half1 + pass1 (min only; tile stays resident for pass2) ----
#pragma unroll
    for (int i = 0; i < 8; ++i) tile[t + 256*i] = pb[2048 + t + 256*i];
    __syncthreads();
#pragma unroll 8
    for (int i = 0; i < 32; ++i) {
        float4 cd = tile[i*64 + l];
        float dot = fmaf(qp.z, cd.z, fmaf(qp.y, cd.y, qp.x*cd.x));
        float d = fmaxf(fmaf(-2.f, dot, qp.w + cd.w), 0.f);
        mn = fminf(mn, d);
    }

    // ---- tau = 16th smallest of the 64 lane-minima (wave bitonic, float) ----
    float v = mn;
#pragma unroll
    for (int k = 2; k <= 64; k <<= 1) {
#pragma unroll
        for (int j = k >> 1; j > 0; j >>= 1) {
            float o = __shfl_xor(v, j, 64);
            float mnv = fminf(v, o), mxv = fmaxf(v, o);
            v = ((((l & j) == 0) == ((l & k) == 0))) ? mnv : mxv;
        }
    }
    float tau = __shfl(v, 15, 64);

    // ---- pass2: ballot-compact survivors ----
    unsigned long long* sb = sbuf + wv*128;
    const unsigned long long lmask = (1ull << l) - 1ull;
    int cnt = 0;
    // half0 from registers
#pragma unroll 8
    for (int i = 0; i < 32; ++i) {
        bool pred = (dst0[i] <= tau);
        unsigned long long m = __ballot(pred);
        if (pred) {
            int pos2 = cnt + __popcll(m & lmask);
            if (pos2 < 128)
                sb[pos2] = ((unsigned long long)__float_as_uint(dst0[i]) << 32)
                           | (unsigned)(i*64 + l);
        }
        cnt += (int)__popcll(m);
    }
    // half1 recomputed from resident tile (bit-identical chain)
#pragma unroll 4
    for (int i = 0; i < 32; ++i) {
        float4 cd = tile[i*64 + l];
        float dot = fmaf(qp.z, cd.z, fmaf(qp.y, cd.y, qp.x*cd.x));
        float d = fmaxf(fmaf(-2.f, dot, qp.w + cd.w), 0.f);
        bool pred = (d <= tau);
        unsigned long long m = __ballot(pred);
        if (pred) {
            int pos2 = cnt + __popcll(m & lmask);
            if (pos2 < 128)
                sb[pos2] = ((unsigned long long)__float_as_uint(d) << 32)
                           | (unsigned)(2048 + i*64 + l);
        }
        cnt += (int)__popcll(m);
    }
    if (cnt > 128) cnt = 128;

    // ---- pass3: sort survivors, write top-16 ----
    unsigned long long pk = (l < cnt) ? sb[l] : ~0ull;
    pk = bsortu64(pk, l);
    if (cnt > 64) {   // wave-uniform, astronomically rare with tight tau
        unsigned long long w2 = (64 + l < cnt) ? sb[64 + l] : ~0ull;
        w2 = bsortu64(w2, l);
        unsigned long long bb = __shfl(w2, (l - 16) & 63, 64);
        unsigned long long nv = (l < 16) ? pk : ((l < 32) ? bb : ~0ull);
        pk = bsortu64(nv, l);
    }
    if (l < 16) idx[grow*16 + l] = (int)(pk & 0xffffffffu);
}

// ---------------- kernel 5: fused per-neighbor MLPs + softmax + agg + out ---------
// block = 256 threads (4 waves) handles 8 points = 128 (n,k) rows.
__global__ __launch_bounds__(256) void k_attn(
    const float* __restrict__ x, const float* __restrict__ pos,
    const float* __restrict__ P1, const float* __restrict__ p1b,
    const float* __restrict__ p2b, const float* __restrict__ a2b,
    const float* __restrict__ A2, const float* __restrict__ Wf,
    const float* __restrict__ bff, const float* __restrict__ ws,
    float* __restrict__ out) {

    __shared__ unsigned short wcombT[128*72];  // Bt: [dd][c]
    __shared__ unsigned short a2T[64*72];      // Bt: [d][e]
    __shared__ unsigned short abuf[128*72];    // h1 then h2, row-major [r][c], stride 72
    __shared__ float relb[128*4];
    __shared__ int   mrow[128];
    __shared__ float aggb[8*64];

    const int t  = threadIdx.x;
    const int g0 = blockIdx.x * 8;
    const int b  = g0 >> 12;
    const float* qA1 = ws + OFS_QA1;
    const float* kA1 = ws + OFS_KA1;
    const float* vws = ws + OFS_V;
    const float* c1  = ws + OFS_C1;
    const int* idx = (const int*)(ws + OFS_IDX);

    for (int i = t; i < 8192; i += 256) {
        int c = i >> 7, dd = i & 127;
        wcombT[dd*72 + c] = f2bf(ws[OFS_WCOMB + i]);
    }
    for (int i = t; i < 4096; i += 256) {
        int e = i >> 6, d = i & 63;
        a2T[d*72 + e] = f2bf(A2[i]);
    }
    if (t < 128) {
        int p = t >> 4, k = t & 15;
        int ng = g0 + p;
        int m  = idx[(size_t)ng*16 + k];
        int mg = b * N_ + m;
        mrow[t] = mg;
        relb[t*4+0] = pos[(size_t)ng*3+0] - pos[(size_t)mg*3+0];
        relb[t*4+1] = pos[(size_t)ng*3+1] - pos[(size_t)mg*3+1];
        relb[t*4+2] = pos[(size_t)ng*3+2] - pos[(size_t)mg*3+2];
    }
    __syncthreads();

    {
        int d = t & 63, r0 = t >> 6;
        float w0 = P1[d], w1 = P1[64+d], w2 = P1[128+d], bb = p1b[d];
#pragma unroll
        for (int jj = 0; jj < 32; ++jj) {
            int r = r0 + jj*4;
            float h = fmaf(relb[r*4+2], w2, fmaf(relb[r*4+1], w1, fmaf(relb[r*4+0], w0, bb)));
            abuf[r*72 + d] = f2bf(fmaxf(h, 0.f));
        }
    }
    __syncthreads();

    const int w = t >> 6, l = t & 63, lr = l & 15, q = l >> 4;

    floatx4 acc1[2][8];
#pragma unroll
    for (int i = 0; i < 2; ++i)
#pragma unroll
        for (int j = 0; j < 8; ++j) acc1[i][j] = (floatx4){0.f, 0.f, 0.f, 0.f};
#pragma unroll
    for (int kb = 0; kb < 2; ++kb) {
        short8 a0 = *(const short8*)&abuf[(32*w      + lr)*72 + 32*kb + 8*q];
        short8 a1 = *(const short8*)&abuf[(32*w + 16 + lr)*72 + 32*kb + 8*q];
#pragma unroll
        for (int j = 0; j < 8; ++j) {
            short8 bfr = *(const short8*)&wcombT[(16*j + lr)*72 + 32*kb + 8*q];
            acc1[0][j] = __builtin_amdgcn_mfma_f32_16x16x32_bf16(a0, bfr, acc1[0][j], 0, 0, 0);
            acc1[1][j] = __builtin_amdgcn_mfma_f32_16x16x32_bf16(a1, bfr, acc1[1][j], 0, 0, 0);
        }
    }
    __syncthreads();

#pragma unroll
    for (int i = 0; i < 2; ++i) {
        int ng = g0 + 2*w + i;
#pragma unroll
        for (int j = 0; j < 4; ++j) {
            int col = 16*j + lr;
            float qv = qA1[(size_t)ng*64 + col] + c1[col];
#pragma unroll
            for (int r = 0; r < 4; ++r) {
                int row = 32*w + 16*i + 4*q + r;
                int mg  = mrow[row];
                float t1 = acc1[i][j][r] + qv - kA1[(size_t)mg*64 + col];
                abuf[row*72 + col] = f2bf(fmaxf(t1, 0.f));
            }
        }
    }
    __syncthreads();

    floatx4 acc2[2][4];
#pragma unroll
    for (int i = 0; i < 2; ++i)
#pragma unroll
        for (int j = 0; j < 4; ++j) acc2[i][j] = (floatx4){0.f, 0.f, 0.f, 0.f};
#pragma unroll
    for (int kb = 0; kb < 2; ++kb) {
        short8 a0 = *(const short8*)&abuf[(32*w      + lr)*72 + 32*kb + 8*q];
        short8 a1 = *(const short8*)&abuf[(32*w + 16 + lr)*72 + 32*kb + 8*q];
#pragma unroll
        for (int j = 0; j < 4; ++j) {
            short8 bfr = *(const short8*)&a2T[(16*j + lr)*72 + 32*kb + 8*q];
            acc2[0][j] = __builtin_amdgcn_mfma_f32_16x16x32_bf16(a0, bfr, acc2[0][j], 0, 0, 0);
            acc2[1][j] = __builtin_amdgcn_mfma_f32_16x16x32_bf16(a1, bfr, acc2[1][j], 0, 0, 0);
        }
    }

#pragma unroll
    for (int i = 0; i < 2; ++i) {
#pragma unroll
        for (int j = 0; j < 4; ++j) {
            int col = 16*j + lr;
            float a2bv = a2b[col], p2bv = p2b[col];
            float L[4];
#pragma unroll
            for (int r = 0; r < 4; ++r) L[r] = acc2[i][j][r] + a2bv;
            float mx = fmaxf(fmaxf(L[0], L[1]), fmaxf(L[2], L[3]));
            mx = fmaxf(mx, __shfl_xor(mx, 16, 64));
            mx = fmaxf(mx, __shfl_xor(mx, 32, 64));
            float ssum = 0.f, part = 0.f;
#pragma unroll
            for (int r = 0; r < 4; ++r) {
                float e = __expf((L[r] - mx) * 0.125f);
                ssum += e;
                int row = 32*w + 16*i + 4*q + r;
                int mg  = mrow[row];
                float wv = vws[(size_t)mg*64 + col] + (acc1[i][4+j][r] + p2bv);
                part = fmaf(e, wv, part);
            }
            ssum += __shfl_xor(ssum, 16, 64);
            ssum += __shfl_xor(ssum, 32, 64);
            part += __shfl_xor(part, 16, 64);
            part += __shfl_xor(part, 32, 64);
            float agg = part / ssum;
            if (q == 0) aggb[(2*w + i)*64 + col] = agg;
        }
    }
    __syncthreads();

    {
        int d = t & 63;
        int p0 = t >> 6;
#pragma unroll
        for (int pp = p0; pp < 8; pp += 4) {
            float s = bff[d];
#pragma unroll 8
            for (int c = 0; c < 64; ++c) s = fmaf(aggb[pp*64 + c], Wf[c*64 + d], s);
            int g = g0 + pp;
            out[(size_t)g*64 + d] = s + x[(size_t)g*64 + d];
        }
    }
}

// ---------------- launch ----------------
extern "C" void kernel_launch(void* const* d_in, const int* in_sizes, int n_in,
                              void* d_out, int out_size, void* d_ws, size_t ws_size,
                              hipStream_t stream) {
    const float* x   = (const float*)d_in[0];
    const float* pos = (const float*)d_in[1];
    const float* Wq  = (const float*)d_in[2];
    const float* Wk  = (const float*)d_in[3];
    const float* Wv  = (const float*)d_in[4];
    const float* P1  = (const float*)d_in[5];
    const float* p1b = (const float*)d_in[6];
    const float* P2  = (const float*)d_in[7];
    const float* p2b = (const float*)d_in[8];
    const float* A1  = (const float*)d_in[9];
    const float* a1b = (const float*)d_in[10];
    const float* A2  = (const float*)d_in[11];
    const float* a2b = (const float*)d_in[12];
    const float* Wf  = (const float*)d_in[13];
    const float* bf  = (const float*)d_in[14];
    float* out = (float*)d_out;
    float* ws  = (float*)d_ws;

    hipLaunchKernelGGL(k_precompute, dim3(65),   dim3(256), 0, stream, Wq, Wk, P2, A1, p2b, a1b, ws);
    hipLaunchKernelGGL(k_pos4,       dim3(64),   dim3(256), 0, stream, pos, ws);
    hipLaunchKernelGGL(k_proj,       dim3(4096), dim3(256), 0, stream, x, Wv, ws);
    hipLaunchKernelGGL(k_knn,        dim3(4096), dim3(256), 0, stream, ws);
    hipLaunchKernelGGL(k_attn,       dim3(2048), dim3(256), 0, stream,
                       x, pos, P1, p1b, p2b, a2b, A2, Wf, bf, ws, out);
}